// Round 2
// baseline (1153.379 us; speedup 1.0000x reference)
//
#include <hip/hip_runtime.h>

#define N_NODES 100000
#define FEAT 64
#define SCAN_B 1024

__global__ void zero_kernel(int* __restrict__ p, int n) {
    int i = blockIdx.x * blockDim.x + threadIdx.x;
    int stride = gridDim.x * blockDim.x;
    for (; i < n; i += stride) p[i] = 0;
}

// Per-edge histogram of dst -> deg counts.
__global__ __launch_bounds__(256) void hist_kernel(
    const int* __restrict__ dst, int* __restrict__ hist, int nE) {
    int e = blockIdx.x * blockDim.x + threadIdx.x;
    if (e < nE) atomicAdd(&hist[dst[e]], 1);
}

// Block-level exclusive scan (Hillis-Steele), partials -> rowptr, totals -> bsum.
__global__ __launch_bounds__(SCAN_B) void scan1_kernel(
    const int* __restrict__ deg, int* __restrict__ rowptr,
    int* __restrict__ bsum, int n) {
    __shared__ int tmp[SCAN_B];
    int t = threadIdx.x;
    int gid = blockIdx.x * SCAN_B + t;
    int v = (gid < n) ? deg[gid] : 0;
    tmp[t] = v;
    __syncthreads();
    for (int off = 1; off < SCAN_B; off <<= 1) {
        int a = (t >= off) ? tmp[t - off] : 0;
        __syncthreads();
        tmp[t] += a;
        __syncthreads();
    }
    if (gid < n) rowptr[gid] = tmp[t] - v;  // exclusive
    if (t == SCAN_B - 1) bsum[blockIdx.x] = tmp[t];
}

// Exclusive scan of <=128 block sums, single block of 128 threads.
__global__ __launch_bounds__(128) void scan2_kernel(int* __restrict__ bsum, int nb) {
    __shared__ int tmp[128];
    int t = threadIdx.x;
    int v = (t < nb) ? bsum[t] : 0;
    tmp[t] = v;
    __syncthreads();
    for (int off = 1; off < 128; off <<= 1) {
        int a = (t >= off) ? tmp[t - off] : 0;
        __syncthreads();
        tmp[t] += a;
        __syncthreads();
    }
    if (t < nb) bsum[t] = tmp[t] - v;  // exclusive
}

// Add block offsets; copy result into fill cursors; set rowptr[n]=total.
__global__ __launch_bounds__(256) void scan3_kernel(
    int* __restrict__ rowptr, int* __restrict__ fill,
    const int* __restrict__ bsum, int n, int total) {
    int gid = blockIdx.x * blockDim.x + threadIdx.x;
    if (gid < n) {
        int v = rowptr[gid] + bsum[gid >> 10];
        rowptr[gid] = v;
        fill[gid] = v;
    }
    if (gid == 0) rowptr[n] = total;
}

// Scatter edges into dst-sorted order: 4B atomic + 4B write per edge
// (vs 256B float RMW per edge in the old scatter).
__global__ __launch_bounds__(256) void fill_kernel(
    const int* __restrict__ src, const int* __restrict__ dst,
    int* __restrict__ fill, int* __restrict__ ssrc, int nE) {
    int e = blockIdx.x * blockDim.x + threadIdx.x;
    if (e < nE) {
        int d = dst[e];
        int pos = atomicAdd(&fill[d], 1);
        ssrc[pos] = src[e];
    }
}

// Fused mean-aggregate + dual matvec + bias + ReLU.
// One wave per node (persistent). Lane f owns output feature f and holds
// weight rows Wl[f][*], Wr[f][*] in 128 VGPRs. mean/x broadcast via __shfl
// (readlane) -> no LDS, no barriers, no agg round-trip through memory.
__global__ __launch_bounds__(256) void sage_fused_kernel(
    const float* __restrict__ feat,
    const int* __restrict__ rowptr,
    const int* __restrict__ ssrc,
    const float* __restrict__ Wl,
    const float* __restrict__ bias,
    const float* __restrict__ Wr,
    float* __restrict__ out,
    int nNodes) {
    int lane = threadIdx.x & 63;

    float4 wl[16], wr[16];
    const float4* Wl4 = (const float4*)(Wl + lane * FEAT);
    const float4* Wr4 = (const float4*)(Wr + lane * FEAT);
#pragma unroll
    for (int i = 0; i < 16; ++i) { wl[i] = Wl4[i]; wr[i] = Wr4[i]; }
    float bv = bias[lane];

    int wave = (blockIdx.x * blockDim.x + threadIdx.x) >> 6;
    int nWaves = (gridDim.x * blockDim.x) >> 6;

    for (int node = wave; node < nNodes; node += nWaves) {
        int beg = rowptr[node];
        int end = rowptr[node + 1];
        int deg = end - beg;

        float acc = 0.0f;
        for (int j0 = beg; j0 < end; j0 += 64) {
            int rem = end - j0;
            int chunk = rem < 64 ? rem : 64;
            int sv = (lane < rem) ? ssrc[j0 + lane] : 0;
            for (int j = 0; j < chunk; ++j) {
                int s = __shfl(sv, j);
                acc += feat[s * FEAT + lane];
            }
        }
        float meanv = acc / (float)(deg > 0 ? deg : 1);
        float xv = feat[node * FEAT + lane];

        float o = bv;
#pragma unroll
        for (int k = 0; k < 16; ++k) {
            o += wl[k].x * __shfl(meanv, 4 * k + 0) + wr[k].x * __shfl(xv, 4 * k + 0);
            o += wl[k].y * __shfl(meanv, 4 * k + 1) + wr[k].y * __shfl(xv, 4 * k + 1);
            o += wl[k].z * __shfl(meanv, 4 * k + 2) + wr[k].z * __shfl(xv, 4 * k + 2);
            o += wl[k].w * __shfl(meanv, 4 * k + 3) + wr[k].w * __shfl(xv, 4 * k + 3);
        }
        out[node * FEAT + lane] = fmaxf(o, 0.0f);
    }
}

extern "C" void kernel_launch(void* const* d_in, const int* in_sizes, int n_in,
                              void* d_out, int out_size, void* d_ws, size_t ws_size,
                              hipStream_t stream) {
    const float* x   = (const float*)d_in[0];
    const int* ei    = (const int*)d_in[1];
    const float* Wl1 = (const float*)d_in[2];
    const float* b1  = (const float*)d_in[3];
    const float* Wr1 = (const float*)d_in[4];
    const float* Wl2 = (const float*)d_in[5];
    const float* b2  = (const float*)d_in[6];
    const float* Wr2 = (const float*)d_in[7];

    const int E = in_sizes[1] / 2;  // 1,600,000
    const int* src = ei;
    const int* dst = ei + E;
    const int N = N_NODES;

    // workspace layout (all 4B-aligned)
    int* hist   = (int*)d_ws;            // N
    int* rowptr = hist + N;              // N+1
    int* bsum   = rowptr + (N + 1);      // 128
    int* fill   = bsum + 128;            // N
    int* ssrc   = fill + N;              // E
    float* h    = (float*)(ssrc + E);    // N*64
    float* out  = (float*)d_out;

    const int NB = (N + SCAN_B - 1) / SCAN_B;  // 98

    // ---- CSR build (once, reused by both layers) ----
    zero_kernel<<<256, 256, 0, stream>>>(hist, N);
    hist_kernel<<<(E + 255) / 256, 256, 0, stream>>>(dst, hist, E);
    scan1_kernel<<<NB, SCAN_B, 0, stream>>>(hist, rowptr, bsum, N);
    scan2_kernel<<<1, 128, 0, stream>>>(bsum, NB);
    scan3_kernel<<<(N + 256) / 256, 256, 0, stream>>>(rowptr, fill, bsum, N, E);
    fill_kernel<<<(E + 255) / 256, 256, 0, stream>>>(src, dst, fill, ssrc, E);

    // ---- fused layers ----
    sage_fused_kernel<<<768, 256, 0, stream>>>(x, rowptr, ssrc, Wl1, b1, Wr1, h, N);
    sage_fused_kernel<<<768, 256, 0, stream>>>(h, rowptr, ssrc, Wl2, b2, Wr2, out, N);
}

// Round 3
// 634.271 us; speedup vs baseline: 1.8184x; 1.8184x over previous
//
#include <hip/hip_runtime.h>

#define N_NODES 100000
#define FEAT 64
#define SCAN_B 1024

__global__ void zero_kernel(int* __restrict__ p, int n) {
    int i = blockIdx.x * blockDim.x + threadIdx.x;
    int stride = gridDim.x * blockDim.x;
    for (; i < n; i += stride) p[i] = 0;
}

// Per-edge histogram of dst -> deg counts.
__global__ __launch_bounds__(256) void hist_kernel(
    const int* __restrict__ dst, int* __restrict__ hist, int nE) {
    int e = blockIdx.x * blockDim.x + threadIdx.x;
    if (e < nE) atomicAdd(&hist[dst[e]], 1);
}

// Block-level exclusive scan (Hillis-Steele), partials -> rowptr, totals -> bsum.
__global__ __launch_bounds__(SCAN_B) void scan1_kernel(
    const int* __restrict__ deg, int* __restrict__ rowptr,
    int* __restrict__ bsum, int n) {
    __shared__ int tmp[SCAN_B];
    int t = threadIdx.x;
    int gid = blockIdx.x * SCAN_B + t;
    int v = (gid < n) ? deg[gid] : 0;
    tmp[t] = v;
    __syncthreads();
    for (int off = 1; off < SCAN_B; off <<= 1) {
        int a = (t >= off) ? tmp[t - off] : 0;
        __syncthreads();
        tmp[t] += a;
        __syncthreads();
    }
    if (gid < n) rowptr[gid] = tmp[t] - v;  // exclusive
    if (t == SCAN_B - 1) bsum[blockIdx.x] = tmp[t];
}

// Exclusive scan of <=128 block sums, single block of 128 threads.
__global__ __launch_bounds__(128) void scan2_kernel(int* __restrict__ bsum, int nb) {
    __shared__ int tmp[128];
    int t = threadIdx.x;
    int v = (t < nb) ? bsum[t] : 0;
    tmp[t] = v;
    __syncthreads();
    for (int off = 1; off < 128; off <<= 1) {
        int a = (t >= off) ? tmp[t - off] : 0;
        __syncthreads();
        tmp[t] += a;
        __syncthreads();
    }
    if (t < nb) bsum[t] = tmp[t] - v;  // exclusive
}

// Add block offsets; copy result into fill cursors; set rowptr[n]=total.
__global__ __launch_bounds__(256) void scan3_kernel(
    int* __restrict__ rowptr, int* __restrict__ fill,
    const int* __restrict__ bsum, int n, int total) {
    int gid = blockIdx.x * blockDim.x + threadIdx.x;
    if (gid < n) {
        int v = rowptr[gid] + bsum[gid >> 10];
        rowptr[gid] = v;
        fill[gid] = v;
    }
    if (gid == 0) rowptr[n] = total;
}

// Scatter edges into dst-sorted order: 4B atomic + 4B write per edge.
__global__ __launch_bounds__(256) void fill_kernel(
    const int* __restrict__ src, const int* __restrict__ dst,
    int* __restrict__ fill, int* __restrict__ ssrc, int nE) {
    int e = blockIdx.x * blockDim.x + threadIdx.x;
    if (e < nE) {
        int d = dst[e];
        int pos = atomicAdd(&fill[d], 1);
        ssrc[pos] = src[e];
    }
}

// Mean aggregation: one quarter-wave (16 lanes) per node, float4 per lane.
// 4 nodes per wave + 4x edge unroll -> >=16 independent row loads in flight
// per wave; low VGPR -> 8 waves/SIMD. No shfl in the hot loop.
__global__ __launch_bounds__(256) void agg_kernel(
    const float* __restrict__ feat,
    const int* __restrict__ rowptr,
    const int* __restrict__ ssrc,
    float* __restrict__ mean_out,
    int nNodes) {
    int tid = blockIdx.x * blockDim.x + threadIdx.x;
    int node = tid >> 4;
    if (node >= nNodes) return;
    int chunk = threadIdx.x & 15;
    const float4* feat4 = (const float4*)feat;

    int beg = rowptr[node];
    int end = rowptr[node + 1];
    float4 acc = make_float4(0.f, 0.f, 0.f, 0.f);

    int j = beg;
    for (; j + 4 <= end; j += 4) {
        int s0 = ssrc[j + 0];
        int s1 = ssrc[j + 1];
        int s2 = ssrc[j + 2];
        int s3 = ssrc[j + 3];
        float4 a0 = feat4[(size_t)s0 * 16 + chunk];
        float4 a1 = feat4[(size_t)s1 * 16 + chunk];
        float4 a2 = feat4[(size_t)s2 * 16 + chunk];
        float4 a3 = feat4[(size_t)s3 * 16 + chunk];
        acc.x += (a0.x + a1.x) + (a2.x + a3.x);
        acc.y += (a0.y + a1.y) + (a2.y + a3.y);
        acc.z += (a0.z + a1.z) + (a2.z + a3.z);
        acc.w += (a0.w + a1.w) + (a2.w + a3.w);
    }
    for (; j < end; ++j) {
        int s = ssrc[j];
        float4 a = feat4[(size_t)s * 16 + chunk];
        acc.x += a.x; acc.y += a.y; acc.z += a.z; acc.w += a.w;
    }

    int deg = end - beg;
    float inv = 1.0f / (float)(deg > 0 ? deg : 1);
    float4 m = make_float4(acc.x * inv, acc.y * inv, acc.z * inv, acc.w * inv);
    ((float4*)mean_out)[(size_t)node * 16 + chunk] = m;
}

// out = relu(W_l @ mean + b + W_r @ x). One wave per node (grid-stride).
// Lane f owns output feature f; weight rows in 128 VGPRs; mean/x broadcast
// via __shfl with constant index (v_readlane -> SGPR operand in the FMA).
// Safe with out == xin: node i's row is read only by the wave writing it.
__global__ __launch_bounds__(256) void linear_kernel(
    const float* __restrict__ mean_in,
    const float* __restrict__ xin,
    const float* __restrict__ Wl,
    const float* __restrict__ bias,
    const float* __restrict__ Wr,
    float* __restrict__ out,
    int nNodes) {
    int lane = threadIdx.x & 63;

    float4 wl[16], wr[16];
    const float4* Wl4 = (const float4*)(Wl + lane * FEAT);
    const float4* Wr4 = (const float4*)(Wr + lane * FEAT);
#pragma unroll
    for (int i = 0; i < 16; ++i) { wl[i] = Wl4[i]; wr[i] = Wr4[i]; }
    float bv = bias[lane];

    int wave = (blockIdx.x * blockDim.x + threadIdx.x) >> 6;
    int nWaves = (gridDim.x * blockDim.x) >> 6;

    for (int node = wave; node < nNodes; node += nWaves) {
        float meanv = mean_in[(size_t)node * FEAT + lane];
        float xv = xin[(size_t)node * FEAT + lane];
        float o = bv;
#pragma unroll
        for (int k = 0; k < 16; ++k) {
            o += wl[k].x * __shfl(meanv, 4 * k + 0) + wr[k].x * __shfl(xv, 4 * k + 0);
            o += wl[k].y * __shfl(meanv, 4 * k + 1) + wr[k].y * __shfl(xv, 4 * k + 1);
            o += wl[k].z * __shfl(meanv, 4 * k + 2) + wr[k].z * __shfl(xv, 4 * k + 2);
            o += wl[k].w * __shfl(meanv, 4 * k + 3) + wr[k].w * __shfl(xv, 4 * k + 3);
        }
        out[(size_t)node * FEAT + lane] = fmaxf(o, 0.0f);
    }
}

extern "C" void kernel_launch(void* const* d_in, const int* in_sizes, int n_in,
                              void* d_out, int out_size, void* d_ws, size_t ws_size,
                              hipStream_t stream) {
    const float* x   = (const float*)d_in[0];
    const int* ei    = (const int*)d_in[1];
    const float* Wl1 = (const float*)d_in[2];
    const float* b1  = (const float*)d_in[3];
    const float* Wr1 = (const float*)d_in[4];
    const float* Wl2 = (const float*)d_in[5];
    const float* b2  = (const float*)d_in[6];
    const float* Wr2 = (const float*)d_in[7];

    const int E = in_sizes[1] / 2;  // 1,600,000
    const int* src = ei;
    const int* dst = ei + E;
    const int N = N_NODES;

    // workspace layout (all 16B-aligned where it matters)
    int* hist    = (int*)d_ws;            // N
    int* rowptr  = hist + N;              // N+1
    int* bsum    = rowptr + (N + 1);      // 128
    int* fill    = bsum + 128;            // N
    int* ssrc    = fill + N;              // E   (offset 300229+128 ints)
    float* meanb = (float*)(ssrc + E);    // N*64, 16B-aligned (offset divisible by 4... )
    float* h     = (float*)d_out;         // reuse d_out as the hidden buffer
    float* out   = (float*)d_out;

    const int NB = (N + SCAN_B - 1) / SCAN_B;  // 98

    // ---- CSR build (once, reused by both layers) ----
    zero_kernel<<<256, 256, 0, stream>>>(hist, N);
    hist_kernel<<<(E + 255) / 256, 256, 0, stream>>>(dst, hist, E);
    scan1_kernel<<<NB, SCAN_B, 0, stream>>>(hist, rowptr, bsum, N);
    scan2_kernel<<<1, 128, 0, stream>>>(bsum, NB);
    scan3_kernel<<<(N + 256) / 256, 256, 0, stream>>>(rowptr, fill, bsum, N, E);
    fill_kernel<<<(E + 255) / 256, 256, 0, stream>>>(src, dst, fill, ssrc, E);

    // ---- layer 1 ----
    agg_kernel<<<(N * 16 + 255) / 256, 256, 0, stream>>>(x, rowptr, ssrc, meanb, N);
    linear_kernel<<<2048, 256, 0, stream>>>(meanb, x, Wl1, b1, Wr1, h, N);

    // ---- layer 2 ----
    agg_kernel<<<(N * 16 + 255) / 256, 256, 0, stream>>>(h, rowptr, ssrc, meanb, N);
    linear_kernel<<<2048, 256, 0, stream>>>(meanb, h, Wl2, b2, Wr2, out, N);
}

// Round 6
// 589.503 us; speedup vs baseline: 1.9565x; 1.0759x over previous
//
#include <hip/hip_runtime.h>

#define N_NODES 100000
#define FEAT 64
#define SCAN_B 1024

__global__ void zero_kernel(int* __restrict__ p, int n) {
    int i = blockIdx.x * blockDim.x + threadIdx.x;
    int stride = gridDim.x * blockDim.x;
    for (; i < n; i += stride) p[i] = 0;
}

// Per-edge histogram of dst -> deg counts.
__global__ __launch_bounds__(256) void hist_kernel(
    const int* __restrict__ dst, int* __restrict__ hist, int nE) {
    int e = blockIdx.x * blockDim.x + threadIdx.x;
    if (e < nE) atomicAdd(&hist[dst[e]], 1);
}

// Block-level exclusive scan (Hillis-Steele), partials -> rowptr, totals -> bsum.
__global__ __launch_bounds__(SCAN_B) void scan1_kernel(
    const int* __restrict__ deg, int* __restrict__ rowptr,
    int* __restrict__ bsum, int n) {
    __shared__ int tmp[SCAN_B];
    int t = threadIdx.x;
    int gid = blockIdx.x * SCAN_B + t;
    int v = (gid < n) ? deg[gid] : 0;
    tmp[t] = v;
    __syncthreads();
    for (int off = 1; off < SCAN_B; off <<= 1) {
        int a = (t >= off) ? tmp[t - off] : 0;
        __syncthreads();
        tmp[t] += a;
        __syncthreads();
    }
    if (gid < n) rowptr[gid] = tmp[t] - v;  // exclusive
    if (t == SCAN_B - 1) bsum[blockIdx.x] = tmp[t];
}

// Exclusive scan of <=128 block sums, single block of 128 threads.
__global__ __launch_bounds__(128) void scan2_kernel(int* __restrict__ bsum, int nb) {
    __shared__ int tmp[128];
    int t = threadIdx.x;
    int v = (t < nb) ? bsum[t] : 0;
    tmp[t] = v;
    __syncthreads();
    for (int off = 1; off < 128; off <<= 1) {
        int a = (t >= off) ? tmp[t - off] : 0;
        __syncthreads();
        tmp[t] += a;
        __syncthreads();
    }
    if (t < nb) bsum[t] = tmp[t] - v;  // exclusive
}

// Add block offsets; copy result into fill cursors; set rowptr[n]=total.
__global__ __launch_bounds__(256) void scan3_kernel(
    int* __restrict__ rowptr, int* __restrict__ fill,
    const int* __restrict__ bsum, int n, int total) {
    int gid = blockIdx.x * blockDim.x + threadIdx.x;
    if (gid < n) {
        int v = rowptr[gid] + bsum[gid >> 10];
        rowptr[gid] = v;
        fill[gid] = v;
    }
    if (gid == 0) rowptr[n] = total;
}

// Scatter edges into dst-sorted order: 4B atomic + 4B write per edge.
__global__ __launch_bounds__(256) void fill_kernel(
    const int* __restrict__ src, const int* __restrict__ dst,
    int* __restrict__ fill, int* __restrict__ ssrc, int nE) {
    int e = blockIdx.x * blockDim.x + threadIdx.x;
    if (e < nE) {
        int d = dst[e];
        int pos = atomicAdd(&fill[d], 1);
        ssrc[pos] = src[e];
    }
}

// Mean aggregation: one quarter-wave (16 lanes) per node, float4 per lane.
// 4 nodes per wave + 4x edge unroll -> >=16 independent row loads in flight
// per wave; low VGPR -> 8 waves/SIMD. No shfl in the hot loop.
__global__ __launch_bounds__(256) void agg_kernel(
    const float* __restrict__ feat,
    const int* __restrict__ rowptr,
    const int* __restrict__ ssrc,
    float* __restrict__ mean_out,
    int nNodes) {
    int tid = blockIdx.x * blockDim.x + threadIdx.x;
    int node = tid >> 4;
    if (node >= nNodes) return;
    int chunk = threadIdx.x & 15;
    const float4* feat4 = (const float4*)feat;

    int beg = rowptr[node];
    int end = rowptr[node + 1];
    float4 acc = make_float4(0.f, 0.f, 0.f, 0.f);

    int j = beg;
    for (; j + 4 <= end; j += 4) {
        int s0 = ssrc[j + 0];
        int s1 = ssrc[j + 1];
        int s2 = ssrc[j + 2];
        int s3 = ssrc[j + 3];
        float4 a0 = feat4[(size_t)s0 * 16 + chunk];
        float4 a1 = feat4[(size_t)s1 * 16 + chunk];
        float4 a2 = feat4[(size_t)s2 * 16 + chunk];
        float4 a3 = feat4[(size_t)s3 * 16 + chunk];
        acc.x += (a0.x + a1.x) + (a2.x + a3.x);
        acc.y += (a0.y + a1.y) + (a2.y + a3.y);
        acc.z += (a0.z + a1.z) + (a2.z + a3.z);
        acc.w += (a0.w + a1.w) + (a2.w + a3.w);
    }
    for (; j < end; ++j) {
        int s = ssrc[j];
        float4 a = feat4[(size_t)s * 16 + chunk];
        acc.x += a.x; acc.y += a.y; acc.z += a.z; acc.w += a.w;
    }

    int deg = end - beg;
    float inv = 1.0f / (float)(deg > 0 ? deg : 1);
    float4 m = make_float4(acc.x * inv, acc.y * inv, acc.z * inv, acc.w * inv);
    ((float4*)mean_out)[(size_t)node * 16 + chunk] = m;
}

// out = relu(W_l @ mean + b + W_r @ x).
// 4 nodes per wave-iteration, 2 accumulators per node (mean-part / x-part)
// -> 8 interleaved FMA chains (latency hidden by issue) + 8 row loads in
// flight. Lane f owns output feature f; weight rows live in 128 VGPRs;
// broadcasts via __shfl with literal lane (v_readlane -> SGPR operand).
// Safe with out == xin: node i's row is read only by the wave writing it.
__global__ __launch_bounds__(256) void linear_kernel(
    const float* __restrict__ mean_in,
    const float* __restrict__ xin,
    const float* __restrict__ Wl,
    const float* __restrict__ bias,
    const float* __restrict__ Wr,
    float* __restrict__ out,
    int nNodes) {
    int lane = threadIdx.x & 63;

    float4 wl[16], wr[16];
    const float4* Wl4 = (const float4*)(Wl + lane * FEAT);
    const float4* Wr4 = (const float4*)(Wr + lane * FEAT);
#pragma unroll
    for (int i = 0; i < 16; ++i) { wl[i] = Wl4[i]; wr[i] = Wr4[i]; }
    float bv = bias[lane];

    int wave = (blockIdx.x * blockDim.x + threadIdx.x) >> 6;
    int nWaves = (gridDim.x * blockDim.x) >> 6;

    // N_NODES % 4 == 0, so every group [n0, n0+3] is fully in range.
    for (int n0 = wave * 4; n0 < nNodes; n0 += nWaves * 4) {
        const float* mrow = mean_in + (size_t)n0 * FEAT + lane;
        const float* xrow = xin + (size_t)n0 * FEAT + lane;
        float m0 = mrow[0], m1 = mrow[FEAT], m2 = mrow[2 * FEAT], m3 = mrow[3 * FEAT];
        float x0 = xrow[0], x1 = xrow[FEAT], x2 = xrow[2 * FEAT], x3 = xrow[3 * FEAT];

        float a0 = bv, a1 = bv, a2 = bv, a3 = bv;   // mean-part (+bias)
        float c0 = 0.f, c1 = 0.f, c2 = 0.f, c3 = 0.f;  // x-part
#pragma unroll
        for (int k = 0; k < 16; ++k) {
            float wlx = wl[k].x, wly = wl[k].y, wlz = wl[k].z, wlw = wl[k].w;
            float wrx = wr[k].x, wry = wr[k].y, wrz = wr[k].z, wrw = wr[k].w;
            a0 += wlx * __shfl(m0, 4 * k + 0); c0 += wrx * __shfl(x0, 4 * k + 0);
            a1 += wlx * __shfl(m1, 4 * k + 0); c1 += wrx * __shfl(x1, 4 * k + 0);
            a2 += wlx * __shfl(m2, 4 * k + 0); c2 += wrx * __shfl(x2, 4 * k + 0);
            a3 += wlx * __shfl(m3, 4 * k + 0); c3 += wrx * __shfl(x3, 4 * k + 0);
            a0 += wly * __shfl(m0, 4 * k + 1); c0 += wry * __shfl(x0, 4 * k + 1);
            a1 += wly * __shfl(m1, 4 * k + 1); c1 += wry * __shfl(x1, 4 * k + 1);
            a2 += wly * __shfl(m2, 4 * k + 1); c2 += wry * __shfl(x2, 4 * k + 1);
            a3 += wly * __shfl(m3, 4 * k + 1); c3 += wry * __shfl(x3, 4 * k + 1);
            a0 += wlz * __shfl(m0, 4 * k + 2); c0 += wrz * __shfl(x0, 4 * k + 2);
            a1 += wlz * __shfl(m1, 4 * k + 2); c1 += wrz * __shfl(x1, 4 * k + 2);
            a2 += wlz * __shfl(m2, 4 * k + 2); c2 += wrz * __shfl(x2, 4 * k + 2);
            a3 += wlz * __shfl(m3, 4 * k + 2); c3 += wrz * __shfl(x3, 4 * k + 2);
            a0 += wlw * __shfl(m0, 4 * k + 3); c0 += wrw * __shfl(x0, 4 * k + 3);
            a1 += wlw * __shfl(m1, 4 * k + 3); c1 += wrw * __shfl(x1, 4 * k + 3);
            a2 += wlw * __shfl(m2, 4 * k + 3); c2 += wrw * __shfl(x2, 4 * k + 3);
            a3 += wlw * __shfl(m3, 4 * k + 3); c3 += wrw * __shfl(x3, 4 * k + 3);
        }
        float* orow = out + (size_t)n0 * FEAT + lane;
        orow[0]        = fmaxf(a0 + c0, 0.0f);
        orow[FEAT]     = fmaxf(a1 + c1, 0.0f);
        orow[2 * FEAT] = fmaxf(a2 + c2, 0.0f);
        orow[3 * FEAT] = fmaxf(a3 + c3, 0.0f);
    }
}

extern "C" void kernel_launch(void* const* d_in, const int* in_sizes, int n_in,
                              void* d_out, int out_size, void* d_ws, size_t ws_size,
                              hipStream_t stream) {
    const float* x   = (const float*)d_in[0];
    const int* ei    = (const int*)d_in[1];
    const float* Wl1 = (const float*)d_in[2];
    const float* b1  = (const float*)d_in[3];
    const float* Wr1 = (const float*)d_in[4];
    const float* Wl2 = (const float*)d_in[5];
    const float* b2  = (const float*)d_in[6];
    const float* Wr2 = (const float*)d_in[7];

    const int E = in_sizes[1] / 2;  // 1,600,000
    const int* src = ei;
    const int* dst = ei + E;
    const int N = N_NODES;

    // workspace layout
    int* hist    = (int*)d_ws;            // N
    int* rowptr  = hist + N;              // N+1
    int* bsum    = rowptr + (N + 1);      // 128
    int* fill    = bsum + 128;            // N
    int* ssrc    = fill + N;              // E
    float* meanb = (float*)(ssrc + E);    // N*64
    float* h     = (float*)d_out;         // reuse d_out as the hidden buffer
    float* out   = (float*)d_out;

    const int NB = (N + SCAN_B - 1) / SCAN_B;  // 98

    // ---- CSR build (once, reused by both layers) ----
    zero_kernel<<<256, 256, 0, stream>>>(hist, N);
    hist_kernel<<<(E + 255) / 256, 256, 0, stream>>>(dst, hist, E);
    scan1_kernel<<<NB, SCAN_B, 0, stream>>>(hist, rowptr, bsum, N);
    scan2_kernel<<<1, 128, 0, stream>>>(bsum, NB);
    scan3_kernel<<<(N + 256) / 256, 256, 0, stream>>>(rowptr, fill, bsum, N, E);
    fill_kernel<<<(E + 255) / 256, 256, 0, stream>>>(src, dst, fill, ssrc, E);

    // ---- layer 1 ----
    agg_kernel<<<(N * 16 + 255) / 256, 256, 0, stream>>>(x, rowptr, ssrc, meanb, N);
    linear_kernel<<<2048, 256, 0, stream>>>(meanb, x, Wl1, b1, Wr1, h, N);

    // ---- layer 2 ----
    agg_kernel<<<(N * 16 + 255) / 256, 256, 0, stream>>>(h, rowptr, ssrc, meanb, N);
    linear_kernel<<<2048, 256, 0, stream>>>(meanb, h, Wl2, b2, Wr2, out, N);
}

// Round 7
// 355.067 us; speedup vs baseline: 3.2483x; 1.6603x over previous
//
#include <hip/hip_runtime.h>
#include <stdint.h>

#define N_NODES 100000
#define FEAT 64
#define SCAN_B 1024

typedef __attribute__((ext_vector_type(8))) short bf16x8;
typedef __attribute__((ext_vector_type(4))) float f32x4;

__global__ void zero_kernel(int* __restrict__ p, int n) {
    int i = blockIdx.x * blockDim.x + threadIdx.x;
    int stride = gridDim.x * blockDim.x;
    for (; i < n; i += stride) p[i] = 0;
}

// Per-edge histogram of dst -> deg counts.
__global__ __launch_bounds__(256) void hist_kernel(
    const int* __restrict__ dst, int* __restrict__ hist, int nE) {
    int e = blockIdx.x * blockDim.x + threadIdx.x;
    if (e < nE) atomicAdd(&hist[dst[e]], 1);
}

// Block-level exclusive scan (Hillis-Steele), partials -> rowptr, totals -> bsum.
__global__ __launch_bounds__(SCAN_B) void scan1_kernel(
    const int* __restrict__ deg, int* __restrict__ rowptr,
    int* __restrict__ bsum, int n) {
    __shared__ int tmp[SCAN_B];
    int t = threadIdx.x;
    int gid = blockIdx.x * SCAN_B + t;
    int v = (gid < n) ? deg[gid] : 0;
    tmp[t] = v;
    __syncthreads();
    for (int off = 1; off < SCAN_B; off <<= 1) {
        int a = (t >= off) ? tmp[t - off] : 0;
        __syncthreads();
        tmp[t] += a;
        __syncthreads();
    }
    if (gid < n) rowptr[gid] = tmp[t] - v;  // exclusive
    if (t == SCAN_B - 1) bsum[blockIdx.x] = tmp[t];
}

// Exclusive scan of <=128 block sums, single block of 128 threads.
__global__ __launch_bounds__(128) void scan2_kernel(int* __restrict__ bsum, int nb) {
    __shared__ int tmp[128];
    int t = threadIdx.x;
    int v = (t < nb) ? bsum[t] : 0;
    tmp[t] = v;
    __syncthreads();
    for (int off = 1; off < 128; off <<= 1) {
        int a = (t >= off) ? tmp[t - off] : 0;
        __syncthreads();
        tmp[t] += a;
        __syncthreads();
    }
    if (t < nb) bsum[t] = tmp[t] - v;  // exclusive
}

// Add block offsets; copy result into fill cursors; set rowptr[n]=total.
__global__ __launch_bounds__(256) void scan3_kernel(
    int* __restrict__ rowptr, int* __restrict__ fill,
    const int* __restrict__ bsum, int n, int total) {
    int gid = blockIdx.x * blockDim.x + threadIdx.x;
    if (gid < n) {
        int v = rowptr[gid] + bsum[gid >> 10];
        rowptr[gid] = v;
        fill[gid] = v;
    }
    if (gid == 0) rowptr[n] = total;
}

// Scatter edges into dst-sorted order: 4B atomic + 4B write per edge.
__global__ __launch_bounds__(256) void fill_kernel(
    const int* __restrict__ src, const int* __restrict__ dst,
    int* __restrict__ fill, int* __restrict__ ssrc, int nE) {
    int e = blockIdx.x * blockDim.x + threadIdx.x;
    if (e < nE) {
        int d = dst[e];
        int pos = atomicAdd(&fill[d], 1);
        ssrc[pos] = src[e];
    }
}

// Mean aggregation: one quarter-wave (16 lanes) per node, float4 per lane.
__global__ __launch_bounds__(256) void agg_kernel(
    const float* __restrict__ feat,
    const int* __restrict__ rowptr,
    const int* __restrict__ ssrc,
    float* __restrict__ mean_out,
    int nNodes) {
    int tid = blockIdx.x * blockDim.x + threadIdx.x;
    int node = tid >> 4;
    if (node >= nNodes) return;
    int chunk = threadIdx.x & 15;
    const float4* feat4 = (const float4*)feat;

    int beg = rowptr[node];
    int end = rowptr[node + 1];
    float4 acc = make_float4(0.f, 0.f, 0.f, 0.f);

    int j = beg;
    for (; j + 4 <= end; j += 4) {
        int s0 = ssrc[j + 0];
        int s1 = ssrc[j + 1];
        int s2 = ssrc[j + 2];
        int s3 = ssrc[j + 3];
        float4 a0 = feat4[(size_t)s0 * 16 + chunk];
        float4 a1 = feat4[(size_t)s1 * 16 + chunk];
        float4 a2 = feat4[(size_t)s2 * 16 + chunk];
        float4 a3 = feat4[(size_t)s3 * 16 + chunk];
        acc.x += (a0.x + a1.x) + (a2.x + a3.x);
        acc.y += (a0.y + a1.y) + (a2.y + a3.y);
        acc.z += (a0.z + a1.z) + (a2.z + a3.z);
        acc.w += (a0.w + a1.w) + (a2.w + a3.w);
    }
    for (; j < end; ++j) {
        int s = ssrc[j];
        float4 a = feat4[(size_t)s * 16 + chunk];
        acc.x += a.x; acc.y += a.y; acc.z += a.z; acc.w += a.w;
    }

    int deg = end - beg;
    float inv = 1.0f / (float)(deg > 0 ? deg : 1);
    float4 m = make_float4(acc.x * inv, acc.y * inv, acc.z * inv, acc.w * inv);
    ((float4*)mean_out)[(size_t)node * 16 + chunk] = m;
}

// ---- MFMA linear: out = relu([mean|x] @ [Wl|Wr]^T + b) ----
// fp32 -> bf16 (RNE), accumulate fp32 in MFMA. No shuffles, no LDS.

__device__ __forceinline__ unsigned short f2bf(float f) {
    unsigned int u = __float_as_uint(f);
    u += 0x7fffu + ((u >> 16) & 1u);   // round-to-nearest-even
    return (unsigned short)(u >> 16);
}

__device__ __forceinline__ bf16x8 pack8(const float* __restrict__ p) {
    float4 a = *(const float4*)p;
    float4 b = *(const float4*)(p + 4);
    bf16x8 r;
    r[0] = (short)f2bf(a.x); r[1] = (short)f2bf(a.y);
    r[2] = (short)f2bf(a.z); r[3] = (short)f2bf(a.w);
    r[4] = (short)f2bf(b.x); r[5] = (short)f2bf(b.y);
    r[6] = (short)f2bf(b.z); r[7] = (short)f2bf(b.w);
    return r;
}

// One wave per 16-node group (grid-stride). A = node data (M=16 rows,
// K=128=[mean|x]), B = weights: B[k][n] = (k<64?Wl:Wr)[n][k&63].
// Fragments (16x16x32 bf16): operand lane l -> row/col l&15, k-block l>>4
// (8 elems); D (m89-verified): col = l&15, row = (l>>4)*4 + reg.
__global__ __launch_bounds__(256) void mfma_linear_kernel(
    const float* __restrict__ mean_in,
    const float* __restrict__ xin,
    const float* __restrict__ Wl,
    const float* __restrict__ bias,
    const float* __restrict__ Wr,
    float* __restrict__ out,
    int nGroups) {
    const int lane = (int)(threadIdx.x & 63);
    const int col = lane & 15;   // B col / A row / D col
    const int kg = lane >> 4;    // k-block within K=32; also D row-block

    // B fragments for all 4 feature tiles x 4 K-steps: 64 VGPRs, loaded once.
    bf16x8 bfr[4][4];
#pragma unroll
    for (int t = 0; t < 4; ++t) {
        const int n = t * 16 + col;
#pragma unroll
        for (int kk = 0; kk < 4; ++kk) {
            const float* w = (kk < 2 ? Wl : Wr) + n * 64 + (kk & 1) * 32 + kg * 8;
            bfr[t][kk] = pack8(w);
        }
    }
    float bv[4];
#pragma unroll
    for (int t = 0; t < 4; ++t) bv[t] = bias[t * 16 + col];

    const int wave = (int)((blockIdx.x * blockDim.x + threadIdx.x) >> 6);
    const int nWaves = (int)((gridDim.x * blockDim.x) >> 6);

    for (int g = wave; g < nGroups; g += nWaves) {
        const int arow = g * 16 + col;  // this lane's A row (node)
        const float* mrow = mean_in + (size_t)arow * FEAT + kg * 8;
        const float* xrow = xin + (size_t)arow * FEAT + kg * 8;

        f32x4 acc[4];
#pragma unroll
        for (int t = 0; t < 4; ++t) acc[t] = (f32x4){0.f, 0.f, 0.f, 0.f};

#pragma unroll
        for (int kk = 0; kk < 4; ++kk) {
            const float* p = (kk < 2) ? (mrow + (kk & 1) * 32) : (xrow + (kk & 1) * 32);
            bf16x8 a = pack8(p);
#pragma unroll
            for (int t = 0; t < 4; ++t)
                acc[t] = __builtin_amdgcn_mfma_f32_16x16x32_bf16(a, bfr[t][kk], acc[t], 0, 0, 0);
        }

        // Writeback: node = g*16 + kg*4 + r, feat = t*16 + col.
        // Safe with out == xin: this group's rows are read/written only by
        // this wave, loads precede stores in program order.
#pragma unroll
        for (int t = 0; t < 4; ++t) {
#pragma unroll
            for (int r = 0; r < 4; ++r) {
                int node = g * 16 + kg * 4 + r;
                out[(size_t)node * FEAT + t * 16 + col] = fmaxf(acc[t][r] + bv[t], 0.0f);
            }
        }
    }
}

extern "C" void kernel_launch(void* const* d_in, const int* in_sizes, int n_in,
                              void* d_out, int out_size, void* d_ws, size_t ws_size,
                              hipStream_t stream) {
    const float* x   = (const float*)d_in[0];
    const int* ei    = (const int*)d_in[1];
    const float* Wl1 = (const float*)d_in[2];
    const float* b1  = (const float*)d_in[3];
    const float* Wr1 = (const float*)d_in[4];
    const float* Wl2 = (const float*)d_in[5];
    const float* b2  = (const float*)d_in[6];
    const float* Wr2 = (const float*)d_in[7];

    const int E = in_sizes[1] / 2;  // 1,600,000
    const int* src = ei;
    const int* dst = ei + E;
    const int N = N_NODES;

    // workspace layout
    int* hist    = (int*)d_ws;            // N
    int* rowptr  = hist + N;              // N+1
    int* bsum    = rowptr + (N + 1);      // 128
    int* fill    = bsum + 128;            // N
    int* ssrc    = fill + N;              // E
    float* meanb = (float*)(((uintptr_t)(ssrc + E) + 15) & ~(uintptr_t)15);  // N*64, 16B-aligned
    float* h     = (float*)d_out;         // reuse d_out as the hidden buffer
    float* out   = (float*)d_out;

    const int NB = (N + SCAN_B - 1) / SCAN_B;  // 98
    const int NG = N / 16;                     // 6250 MFMA node-groups

    // ---- CSR build (once, reused by both layers) ----
    zero_kernel<<<256, 256, 0, stream>>>(hist, N);
    hist_kernel<<<(E + 255) / 256, 256, 0, stream>>>(dst, hist, E);
    scan1_kernel<<<NB, SCAN_B, 0, stream>>>(hist, rowptr, bsum, N);
    scan2_kernel<<<1, 128, 0, stream>>>(bsum, NB);
    scan3_kernel<<<(N + 256) / 256, 256, 0, stream>>>(rowptr, fill, bsum, N, E);
    fill_kernel<<<(E + 255) / 256, 256, 0, stream>>>(src, dst, fill, ssrc, E);

    // ---- layer 1 ----
    agg_kernel<<<(N * 16 + 255) / 256, 256, 0, stream>>>(x, rowptr, ssrc, meanb, N);
    mfma_linear_kernel<<<256, 256, 0, stream>>>(meanb, x, Wl1, b1, Wr1, h, NG);

    // ---- layer 2 ----
    agg_kernel<<<(N * 16 + 255) / 256, 256, 0, stream>>>(h, rowptr, ssrc, meanb, N);
    mfma_linear_kernel<<<256, 256, 0, stream>>>(meanb, h, Wl2, b2, Wr2, out, NG);
}